// Round 1
// baseline (862.388 us; speedup 1.0000x reference)
//
#include <hip/hip_runtime.h>
#include <hip/hip_bf16.h>
#include <math.h>

// Problem constants
#define Bb 4
#define Tt 1024
#define Cc 1024
#define Hh 16
#define Dd 64
// tokens M = Bb*Tt = 4096

struct GemmPtrs {
    const float* W[3];
    const float* bias[3];
    float* out[3];
};

// ---------------------------------------------------------------------------
// fp32 GEMM: out[z] = A[4096,1024] @ W[z][1024,1024] + bias[z]
// BM=128, BN=128, BK=8, 256 threads, 8x8 micro-tile per thread.
// grid = (N/128=8, M/128=32, nmats)
// ---------------------------------------------------------------------------
__global__ __launch_bounds__(256) void gemm_bias_kernel(const float* __restrict__ A, GemmPtrs p)
{
    constexpr int N = 1024, K = 1024;
    constexpr int BM = 128, BN = 128, BK = 8;

    const float* __restrict__ W    = p.W[blockIdx.z];
    const float* __restrict__ bias = p.bias[blockIdx.z];
    float* __restrict__ out        = p.out[blockIdx.z];

    __shared__ float As[BK][BM + 4];   // As[k][m] (transposed store)
    __shared__ float Bs[BK][BN + 4];   // Bs[k][n]

    const int tid = threadIdx.x;
    const int tx = tid & 15;          // 0..15 -> output cols tx*8..
    const int ty = tid >> 4;          // 0..15 -> output rows ty*8..
    const int bm = blockIdx.y * BM;
    const int bn = blockIdx.x * BN;

    // staging load indices
    const int am  = tid >> 1;          // 0..127 (row within A tile)
    const int ak  = (tid & 1) * 4;     // 0 or 4 (col within A tile)
    const int bk  = tid >> 5;          // 0..7   (row within B tile)
    const int bn0 = (tid & 31) * 4;    // 0..124 (col within B tile)

    const float* Aptr = A + (size_t)(bm + am) * K + ak;
    const float* Wptr = W + (size_t)bk * N + bn + bn0;

    float acc[8][8] = {};

    for (int kt = 0; kt < K; kt += BK) {
        float4 av = *(const float4*)(Aptr + kt);
        float4 bv = *(const float4*)(Wptr + (size_t)kt * N);
        __syncthreads();
        As[ak + 0][am] = av.x;
        As[ak + 1][am] = av.y;
        As[ak + 2][am] = av.z;
        As[ak + 3][am] = av.w;
        *(float4*)&Bs[bk][bn0] = bv;
        __syncthreads();

#pragma unroll
        for (int kk = 0; kk < BK; ++kk) {
            float4 a0 = *(const float4*)&As[kk][ty * 8];
            float4 a1 = *(const float4*)&As[kk][ty * 8 + 4];
            float4 b0 = *(const float4*)&Bs[kk][tx * 8];
            float4 b1 = *(const float4*)&Bs[kk][tx * 8 + 4];
            float a[8] = {a0.x, a0.y, a0.z, a0.w, a1.x, a1.y, a1.z, a1.w};
            float b[8] = {b0.x, b0.y, b0.z, b0.w, b1.x, b1.y, b1.z, b1.w};
#pragma unroll
            for (int i = 0; i < 8; ++i)
#pragma unroll
                for (int j = 0; j < 8; ++j)
                    acc[i][j] += a[i] * b[j];
        }
    }

#pragma unroll
    for (int i = 0; i < 8; ++i) {
        const int row = bm + ty * 8 + i;
        float* orow = out + (size_t)row * N + bn + tx * 8;
        const float* brow = bias + bn + tx * 8;
        float4 o0, o1;
        o0.x = acc[i][0] + brow[0];
        o0.y = acc[i][1] + brow[1];
        o0.z = acc[i][2] + brow[2];
        o0.w = acc[i][3] + brow[3];
        o1.x = acc[i][4] + brow[4];
        o1.y = acc[i][5] + brow[5];
        o1.z = acc[i][6] + brow[6];
        o1.w = acc[i][7] + brow[7];
        *(float4*)(orow)     = o0;
        *(float4*)(orow + 4) = o1;
    }
}

// ---------------------------------------------------------------------------
// Flash-style masked attention, fp32.
// q,k,v,y all in [B,T,C] layout (head h at column offset h*D).
// Block: 256 threads handles 64 query rows for one (b,h); iterates 16 key
// tiles of 64. Online softmax reproduces reference -1e9 masking semantics
// exactly (all-masked query rows degrade to uniform weights over ALL keys).
// grid = (T/64=16, B*H=64)
// ---------------------------------------------------------------------------
__global__ __launch_bounds__(256) void attn_kernel(
    const float* __restrict__ q, const float* __restrict__ k,
    const float* __restrict__ v, const float* __restrict__ padj,
    float* __restrict__ y)
{
    __shared__ float Qs[64][68];   // [d][qrow]  (transposed)
    __shared__ float KPs[64][68];  // phase 1: K transposed [d][key]; phase 2: P [qrow][key]
    __shared__ float Vs[64][68];   // [key][d]
    __shared__ float keepq_s[64];
    __shared__ float keepk_s[64];

    const int tid = threadIdx.x;
    const int tx = tid & 15;   // key-col / d-col group
    const int ty = tid >> 4;   // query-row group
    const int q0 = blockIdx.x * 64;
    const int bh = blockIdx.y;
    const int b  = bh >> 4;
    const int h  = bh & 15;
    const size_t base = (size_t)b * Tt * Cc + (size_t)h * Dd;

    // ---- load Q tile (transposed) + keepq ----
    {
        const int r  = tid >> 2;           // 0..63 row
        const int d4 = (tid & 3) * 16;     // 16-float chunk start
        const float* qp = q + base + (size_t)(q0 + r) * Cc + d4;
#pragma unroll
        for (int ii = 0; ii < 4; ++ii) {
            float4 t4 = *(const float4*)(qp + ii * 4);
            const int d = d4 + ii * 4;
            Qs[d + 0][r] = t4.x;
            Qs[d + 1][r] = t4.y;
            Qs[d + 2][r] = t4.z;
            Qs[d + 3][r] = t4.w;
        }
        if (tid < 64) keepq_s[tid] = 1.0f - padj[b * Tt + q0 + tid];
    }
    __syncthreads();

    float kq[4];
#pragma unroll
    for (int i = 0; i < 4; ++i) kq[i] = keepq_s[ty * 4 + i];

    float m_i[4], l_i[4];
    float o[4][4] = {};
#pragma unroll
    for (int i = 0; i < 4; ++i) { m_i[i] = -INFINITY; l_i[i] = 0.0f; }

    const float scale = 0.125f;  // 1/sqrt(64)

    for (int kt = 0; kt < Tt; kt += 64) {
        __syncthreads();  // previous tile's PV readers done before overwrite

        // ---- load K tile (transposed), V tile, keepk ----
        {
            const int r  = tid >> 2;
            const int d4 = (tid & 3) * 16;
            const float* kp = k + base + (size_t)(kt + r) * Cc + d4;
            const float* vp = v + base + (size_t)(kt + r) * Cc + d4;
#pragma unroll
            for (int ii = 0; ii < 4; ++ii) {
                float4 t4 = *(const float4*)(kp + ii * 4);
                const int d = d4 + ii * 4;
                KPs[d + 0][r] = t4.x;
                KPs[d + 1][r] = t4.y;
                KPs[d + 2][r] = t4.z;
                KPs[d + 3][r] = t4.w;
                float4 v4 = *(const float4*)(vp + ii * 4);
                *(float4*)&Vs[r][d] = v4;
            }
            if (tid < 64) keepk_s[tid] = 1.0f - padj[b * Tt + kt + tid];
        }
        __syncthreads();

        // ---- S = Q @ K^T (this thread: rows ty*4.., cols tx*4..) ----
        float s[4][4] = {};
#pragma unroll 8
        for (int d = 0; d < 64; ++d) {
            float4 qa = *(const float4*)&Qs[d][ty * 4];
            float4 kb = *(const float4*)&KPs[d][tx * 4];
            float av[4] = {qa.x, qa.y, qa.z, qa.w};
            float bv[4] = {kb.x, kb.y, kb.z, kb.w};
#pragma unroll
            for (int i = 0; i < 4; ++i)
#pragma unroll
                for (int j = 0; j < 4; ++j)
                    s[i][j] += av[i] * bv[j];
        }

        // mask + scale (reference: where(keep_q*keep_k == 0, -1e9, s*scale))
        float kkc[4];
#pragma unroll
        for (int j = 0; j < 4; ++j) kkc[j] = keepk_s[tx * 4 + j];
#pragma unroll
        for (int i = 0; i < 4; ++i)
#pragma unroll
            for (int j = 0; j < 4; ++j)
                s[i][j] = (kq[i] * kkc[j] == 0.0f) ? -1e9f : s[i][j] * scale;

        // ---- online softmax update ----
        float alpha[4];
        float pr[4][4];
#pragma unroll
        for (int i = 0; i < 4; ++i) {
            float rmax = fmaxf(fmaxf(s[i][0], s[i][1]), fmaxf(s[i][2], s[i][3]));
#pragma unroll
            for (int off = 1; off < 16; off <<= 1)
                rmax = fmaxf(rmax, __shfl_xor(rmax, off, 16));
            const float m_new = fmaxf(m_i[i], rmax);
            alpha[i] = __expf(m_i[i] - m_new);   // exp(-inf)=0 first tile
            m_i[i] = m_new;
            float rsum = 0.0f;
#pragma unroll
            for (int j = 0; j < 4; ++j) {
                pr[i][j] = __expf(s[i][j] - m_new);  // masked: exp(-1e9-m)->0; all-masked row: exp(0)=1
                rsum += pr[i][j];
            }
#pragma unroll
            for (int off = 1; off < 16; off <<= 1)
                rsum += __shfl_xor(rsum, off, 16);
            l_i[i] = l_i[i] * alpha[i] + rsum;
#pragma unroll
            for (int j = 0; j < 4; ++j) o[i][j] *= alpha[i];
        }

        __syncthreads();  // everyone done reading K from KPs

        // ---- write P into KPs (as [qrow][key]) ----
#pragma unroll
        for (int i = 0; i < 4; ++i)
#pragma unroll
            for (int j = 0; j < 4; ++j)
                KPs[ty * 4 + i][tx * 4 + j] = pr[i][j];
        __syncthreads();

        // ---- O += P @ V  (this thread: rows ty*4.., d-cols tx*4..) ----
#pragma unroll
        for (int kv = 0; kv < 64; kv += 4) {
            float4 pf[4];
#pragma unroll
            for (int i = 0; i < 4; ++i)
                pf[i] = *(const float4*)&KPs[ty * 4 + i][kv];
#pragma unroll
            for (int c = 0; c < 4; ++c) {
                float4 vb = *(const float4*)&Vs[kv + c][tx * 4];
                float pc[4] = {pf[0].x, pf[1].x, pf[2].x, pf[3].x};
                if (c == 1) { pc[0] = pf[0].y; pc[1] = pf[1].y; pc[2] = pf[2].y; pc[3] = pf[3].y; }
                if (c == 2) { pc[0] = pf[0].z; pc[1] = pf[1].z; pc[2] = pf[2].z; pc[3] = pf[3].z; }
                if (c == 3) { pc[0] = pf[0].w; pc[1] = pf[1].w; pc[2] = pf[2].w; pc[3] = pf[3].w; }
#pragma unroll
                for (int i = 0; i < 4; ++i) {
                    o[i][0] += pc[i] * vb.x;
                    o[i][1] += pc[i] * vb.y;
                    o[i][2] += pc[i] * vb.z;
                    o[i][3] += pc[i] * vb.w;
                }
            }
        }
    }

    // ---- epilogue: y = O / l ----
#pragma unroll
    for (int i = 0; i < 4; ++i) {
        const int qrow = q0 + ty * 4 + i;
        const float inv = 1.0f / l_i[i];
        float4 r;
        r.x = o[i][0] * inv;
        r.y = o[i][1] * inv;
        r.z = o[i][2] * inv;
        r.w = o[i][3] * inv;
        *(float4*)(y + base + (size_t)qrow * Cc + tx * 4) = r;
    }
}

// ---------------------------------------------------------------------------
extern "C" void kernel_launch(void* const* d_in, const int* in_sizes, int n_in,
                              void* d_out, int out_size, void* d_ws, size_t ws_size,
                              hipStream_t stream)
{
    const float* x    = (const float*)d_in[0];
    const float* padj = (const float*)d_in[1];
    const float* Wq   = (const float*)d_in[2];
    const float* bq   = (const float*)d_in[3];
    const float* Wk   = (const float*)d_in[4];
    const float* bk   = (const float*)d_in[5];
    const float* Wv   = (const float*)d_in[6];
    const float* bv   = (const float*)d_in[7];
    const float* Wp   = (const float*)d_in[8];
    const float* bp   = (const float*)d_in[9];
    float* out = (float*)d_out;

    float* ws = (float*)d_ws;
    const size_t mat = (size_t)Bb * Tt * Cc;  // 4M floats
    float* qbuf = ws;
    float* kbuf = ws + mat;
    float* vbuf = ws + 2 * mat;
    float* ybuf = ws + 3 * mat;

    // QKV projections (fused via grid.z)
    GemmPtrs gp;
    gp.W[0] = Wq;  gp.W[1] = Wk;  gp.W[2] = Wv;
    gp.bias[0] = bq; gp.bias[1] = bk; gp.bias[2] = bv;
    gp.out[0] = qbuf; gp.out[1] = kbuf; gp.out[2] = vbuf;
    gemm_bias_kernel<<<dim3(8, 32, 3), 256, 0, stream>>>(x, gp);

    // masked attention
    attn_kernel<<<dim3(Tt / 64, Bb * Hh), 256, 0, stream>>>(qbuf, kbuf, vbuf, padj, ybuf);

    // output projection
    GemmPtrs gp2;
    gp2.W[0] = Wp; gp2.W[1] = Wp; gp2.W[2] = Wp;
    gp2.bias[0] = bp; gp2.bias[1] = bp; gp2.bias[2] = bp;
    gp2.out[0] = out; gp2.out[1] = out; gp2.out[2] = out;
    gemm_bias_kernel<<<dim3(8, 32, 1), 256, 0, stream>>>(ybuf, gp2);
}

// Round 2
// 536.316 us; speedup vs baseline: 1.6080x; 1.6080x over previous
//
#include <hip/hip_runtime.h>
#include <hip/hip_bf16.h>
#include <math.h>

// Problem constants
#define Bb 4
#define Tt 1024
#define Cc 1024
#define Hh 16
#define Dd 64
#define K3 3072   // compensated-bf16 extended K: [hi | lo | hi]

typedef __attribute__((ext_vector_type(8))) short short8;
typedef __attribute__((ext_vector_type(4))) float floatx4;

__device__ __forceinline__ ushort bf16_rne(float f) {
    union { float f; unsigned u; } v; v.f = f;
    unsigned u = v.u;
    u += 0x7fffu + ((u >> 16) & 1u);
    return (ushort)(u >> 16);
}
__device__ __forceinline__ float bf16_to_f(ushort h) {
    union { float f; unsigned u; } v; v.u = ((unsigned)h) << 16;
    return v.f;
}

__device__ __forceinline__ void gl2lds16(const short* g, short* l) {
    __builtin_amdgcn_global_load_lds(
        (const __attribute__((address_space(1))) void*)g,
        (__attribute__((address_space(3))) void*)l,
        16, 0, 0);
}

// ---------------------------------------------------------------------------
// split_hi_lo: src [4096][1024] fp32  ->  dst [4096][3072] bf16 = [hi | lo | hi]
// grid 4096 x 256; each thread converts 4 consecutive floats.
// ---------------------------------------------------------------------------
__global__ __launch_bounds__(256) void split_hi_lo(const float* __restrict__ src,
                                                   short* __restrict__ dst)
{
    const size_t gt  = (size_t)blockIdx.x * 256 + threadIdx.x;
    const size_t idx = gt * 4;
    const size_t m   = idx >> 10;
    const int    k   = (int)(idx & 1023);
    float4 f = *(const float4*)(src + idx);
    float fv[4] = {f.x, f.y, f.z, f.w};
    ushort hv[4], lv[4];
#pragma unroll
    for (int i = 0; i < 4; ++i) {
        hv[i] = bf16_rne(fv[i]);
        lv[i] = bf16_rne(fv[i] - bf16_to_f(hv[i]));
    }
    ushort4 h4 = make_ushort4(hv[0], hv[1], hv[2], hv[3]);
    ushort4 l4 = make_ushort4(lv[0], lv[1], lv[2], lv[3]);
    ushort* row = (ushort*)dst + m * K3 + k;
    *(ushort4*)(row)        = h4;
    *(ushort4*)(row + 1024) = l4;
    *(ushort4*)(row + 2048) = h4;
}

// ---------------------------------------------------------------------------
// transpose_split: W [1024][1024] fp32 (K-major, x@W convention) ->
//   Bt [1024][3072] bf16 where Bt[n][k] = hi(W[k][n]) | hi | lo  (K-sections)
// grid (16,16,4) x 256; 64x64 tiles through LDS.
// ---------------------------------------------------------------------------
struct WPtrs { const float* W[4]; short* Bt[4]; };

__global__ __launch_bounds__(256) void transpose_split(WPtrs p)
{
    const float* __restrict__ W  = p.W[blockIdx.z];
    short* __restrict__       Bt = p.Bt[blockIdx.z];
    __shared__ float tile[64][65];
    const int k0  = blockIdx.y * 64;
    const int n0  = blockIdx.x * 64;
    const int tr  = threadIdx.x >> 4;         // 0..15
    const int tc4 = (threadIdx.x & 15) * 4;   // 0..60

#pragma unroll
    for (int i = 0; i < 4; ++i) {
        const int kk = tr + i * 16;
        float4 v = *(const float4*)(W + (size_t)(k0 + kk) * 1024 + n0 + tc4);
        tile[kk][tc4 + 0] = v.x;
        tile[kk][tc4 + 1] = v.y;
        tile[kk][tc4 + 2] = v.z;
        tile[kk][tc4 + 3] = v.w;
    }
    __syncthreads();
#pragma unroll
    for (int i = 0; i < 4; ++i) {
        const int n = tr + i * 16;
        ushort hv[4], lv[4];
#pragma unroll
        for (int c = 0; c < 4; ++c) {
            const float f = tile[tc4 + c][n];
            hv[c] = bf16_rne(f);
            lv[c] = bf16_rne(f - bf16_to_f(hv[c]));
        }
        ushort4 h4 = make_ushort4(hv[0], hv[1], hv[2], hv[3]);
        ushort4 l4 = make_ushort4(lv[0], lv[1], lv[2], lv[3]);
        ushort* row = (ushort*)Bt + (size_t)(n0 + n) * K3 + k0 + tc4;
        *(ushort4*)(row)        = h4;
        *(ushort4*)(row + 1024) = h4;
        *(ushort4*)(row + 2048) = l4;
    }
}

// ---------------------------------------------------------------------------
// MFMA GEMM (m97 structure): C[4096][1024] = A'[4096][3072]bf16 @ Bt'[1024][3072]bf16^T + bias
// 128x128 tile, BK=32, 256 threads = 4 waves (2x2 of 64x64), 16x16x32 bf16 MFMA.
// Staging via global_load_lds width 16 (LDS layout = plain row-major [128][32]).
// grid = (8, 32, nmats)
// ---------------------------------------------------------------------------
struct GemmB { const short* Bt[3]; const float* bias[3]; float* out[3]; };

__global__ __launch_bounds__(256) void gemm_mfma(const short* __restrict__ A, GemmB p)
{
    constexpr int N = 1024;
    const short* __restrict__ Bt   = p.Bt[blockIdx.z];
    const float* __restrict__ bias = p.bias[blockIdx.z];
    float* __restrict__       out  = p.out[blockIdx.z];

    __shared__ short As[128 * 32];
    __shared__ short Bs[128 * 32];

    const int tid  = threadIdx.x;
    const int lane = tid & 63;
    const int w    = tid >> 6;
    const int wr   = w >> 1, wc = w & 1;
    const int bm   = blockIdx.y * 128;
    const int bn   = blockIdx.x * 128;

    // staging: 512 16B-chunks per tile; wave w stages chunks [w*128, w*128+128)
    // chunk s -> tile row s>>2, k-chunk s&3; LDS dest = chunk_index*16 bytes
    const int s0 = w * 128 + lane;
    const int s1 = s0 + 64;
    const short* Ag0 = A  + (size_t)(bm + (s0 >> 2)) * K3 + (s0 & 3) * 8;
    const short* Ag1 = A  + (size_t)(bm + (s1 >> 2)) * K3 + (s1 & 3) * 8;
    const short* Bg0 = Bt + (size_t)(bn + (s0 >> 2)) * K3 + (s0 & 3) * 8;
    const short* Bg1 = Bt + (size_t)(bn + (s1 >> 2)) * K3 + (s1 & 3) * 8;
    short* Asd0 = As + w * 1024;
    short* Asd1 = As + w * 1024 + 512;
    short* Bsd0 = Bs + w * 1024;
    short* Bsd1 = Bs + w * 1024 + 512;

    const int mrow = lane & 15;
    const int quad = lane >> 4;

    floatx4 acc[4][4];
#pragma unroll
    for (int i = 0; i < 4; ++i)
#pragma unroll
        for (int j = 0; j < 4; ++j)
            acc[i][j] = (floatx4){0.f, 0.f, 0.f, 0.f};

    for (int kt = 0; kt < K3; kt += 32) {
        gl2lds16(Ag0 + kt, Asd0);
        gl2lds16(Ag1 + kt, Asd1);
        gl2lds16(Bg0 + kt, Bsd0);
        gl2lds16(Bg1 + kt, Bsd1);
        __syncthreads();

        short8 a[4], b[4];
#pragma unroll
        for (int i = 0; i < 4; ++i)
            a[i] = *(const short8*)&As[(wr * 64 + i * 16 + mrow) * 32 + quad * 8];
#pragma unroll
        for (int j = 0; j < 4; ++j)
            b[j] = *(const short8*)&Bs[(wc * 64 + j * 16 + mrow) * 32 + quad * 8];

#pragma unroll
        for (int i = 0; i < 4; ++i)
#pragma unroll
            for (int j = 0; j < 4; ++j)
                acc[i][j] = __builtin_amdgcn_mfma_f32_16x16x32_bf16(a[i], b[j], acc[i][j], 0, 0, 0);

        __syncthreads();
    }

    // epilogue: C/D layout col = lane&15, row = quad*4 + reg
#pragma unroll
    for (int j = 0; j < 4; ++j) {
        const int col = bn + wc * 64 + j * 16 + mrow;
        const float bj = bias[col];
#pragma unroll
        for (int i = 0; i < 4; ++i) {
            const int row = bm + wr * 64 + i * 16 + quad * 4;
            float* o = out + (size_t)row * N + col;
#pragma unroll
            for (int r = 0; r < 4; ++r)
                o[(size_t)r * N] = acc[i][j][r] + bj;
        }
    }
}

// ---------------------------------------------------------------------------
// Flash-style masked attention, fp32 (verified in round 1).
// grid = (T/64=16, B*H=64), 256 threads.
// ---------------------------------------------------------------------------
__global__ __launch_bounds__(256) void attn_kernel(
    const float* __restrict__ q, const float* __restrict__ k,
    const float* __restrict__ v, const float* __restrict__ padj,
    float* __restrict__ y)
{
    __shared__ float Qs[64][68];   // [d][qrow]  (transposed)
    __shared__ float KPs[64][68];  // phase 1: K transposed [d][key]; phase 2: P [qrow][key]
    __shared__ float Vs[64][68];   // [key][d]
    __shared__ float keepq_s[64];
    __shared__ float keepk_s[64];

    const int tid = threadIdx.x;
    const int tx = tid & 15;
    const int ty = tid >> 4;
    const int q0 = blockIdx.x * 64;
    const int bh = blockIdx.y;
    const int b  = bh >> 4;
    const int h  = bh & 15;
    const size_t base = (size_t)b * Tt * Cc + (size_t)h * Dd;

    {
        const int r  = tid >> 2;
        const int d4 = (tid & 3) * 16;
        const float* qp = q + base + (size_t)(q0 + r) * Cc + d4;
#pragma unroll
        for (int ii = 0; ii < 4; ++ii) {
            float4 t4 = *(const float4*)(qp + ii * 4);
            const int d = d4 + ii * 4;
            Qs[d + 0][r] = t4.x;
            Qs[d + 1][r] = t4.y;
            Qs[d + 2][r] = t4.z;
            Qs[d + 3][r] = t4.w;
        }
        if (tid < 64) keepq_s[tid] = 1.0f - padj[b * Tt + q0 + tid];
    }
    __syncthreads();

    float kq[4];
#pragma unroll
    for (int i = 0; i < 4; ++i) kq[i] = keepq_s[ty * 4 + i];

    float m_i[4], l_i[4];
    float o[4][4] = {};
#pragma unroll
    for (int i = 0; i < 4; ++i) { m_i[i] = -INFINITY; l_i[i] = 0.0f; }

    const float scale = 0.125f;

    for (int kt = 0; kt < Tt; kt += 64) {
        __syncthreads();

        {
            const int r  = tid >> 2;
            const int d4 = (tid & 3) * 16;
            const float* kp = k + base + (size_t)(kt + r) * Cc + d4;
            const float* vp = v + base + (size_t)(kt + r) * Cc + d4;
#pragma unroll
            for (int ii = 0; ii < 4; ++ii) {
                float4 t4 = *(const float4*)(kp + ii * 4);
                const int d = d4 + ii * 4;
                KPs[d + 0][r] = t4.x;
                KPs[d + 1][r] = t4.y;
                KPs[d + 2][r] = t4.z;
                KPs[d + 3][r] = t4.w;
                float4 v4 = *(const float4*)(vp + ii * 4);
                *(float4*)&Vs[r][d] = v4;
            }
            if (tid < 64) keepk_s[tid] = 1.0f - padj[b * Tt + kt + tid];
        }
        __syncthreads();

        float s[4][4] = {};
#pragma unroll 8
        for (int d = 0; d < 64; ++d) {
            float4 qa = *(const float4*)&Qs[d][ty * 4];
            float4 kb = *(const float4*)&KPs[d][tx * 4];
            float av[4] = {qa.x, qa.y, qa.z, qa.w};
            float bv[4] = {kb.x, kb.y, kb.z, kb.w};
#pragma unroll
            for (int i = 0; i < 4; ++i)
#pragma unroll
                for (int j = 0; j < 4; ++j)
                    s[i][j] += av[i] * bv[j];
        }

        float kkc[4];
#pragma unroll
        for (int j = 0; j < 4; ++j) kkc[j] = keepk_s[tx * 4 + j];
#pragma unroll
        for (int i = 0; i < 4; ++i)
#pragma unroll
            for (int j = 0; j < 4; ++j)
                s[i][j] = (kq[i] * kkc[j] == 0.0f) ? -1e9f : s[i][j] * scale;

        float alpha[4];
        float pr[4][4];
#pragma unroll
        for (int i = 0; i < 4; ++i) {
            float rmax = fmaxf(fmaxf(s[i][0], s[i][1]), fmaxf(s[i][2], s[i][3]));
#pragma unroll
            for (int off = 1; off < 16; off <<= 1)
                rmax = fmaxf(rmax, __shfl_xor(rmax, off, 16));
            const float m_new = fmaxf(m_i[i], rmax);
            alpha[i] = __expf(m_i[i] - m_new);
            m_i[i] = m_new;
            float rsum = 0.0f;
#pragma unroll
            for (int j = 0; j < 4; ++j) {
                pr[i][j] = __expf(s[i][j] - m_new);
                rsum += pr[i][j];
            }
#pragma unroll
            for (int off = 1; off < 16; off <<= 1)
                rsum += __shfl_xor(rsum, off, 16);
            l_i[i] = l_i[i] * alpha[i] + rsum;
#pragma unroll
            for (int j = 0; j < 4; ++j) o[i][j] *= alpha[i];
        }

        __syncthreads();

#pragma unroll
        for (int i = 0; i < 4; ++i)
#pragma unroll
            for (int j = 0; j < 4; ++j)
                KPs[ty * 4 + i][tx * 4 + j] = pr[i][j];
        __syncthreads();

#pragma unroll
        for (int kv = 0; kv < 64; kv += 4) {
            float4 pf[4];
#pragma unroll
            for (int i = 0; i < 4; ++i)
                pf[i] = *(const float4*)&KPs[ty * 4 + i][kv];
#pragma unroll
            for (int c = 0; c < 4; ++c) {
                float4 vb = *(const float4*)&Vs[kv + c][tx * 4];
                float pc[4] = {pf[0].x, pf[1].x, pf[2].x, pf[3].x};
                if (c == 1) { pc[0] = pf[0].y; pc[1] = pf[1].y; pc[2] = pf[2].y; pc[3] = pf[3].y; }
                if (c == 2) { pc[0] = pf[0].z; pc[1] = pf[1].z; pc[2] = pf[2].z; pc[3] = pf[3].z; }
                if (c == 3) { pc[0] = pf[0].w; pc[1] = pf[1].w; pc[2] = pf[2].w; pc[3] = pf[3].w; }
#pragma unroll
                for (int i = 0; i < 4; ++i) {
                    o[i][0] += pc[i] * vb.x;
                    o[i][1] += pc[i] * vb.y;
                    o[i][2] += pc[i] * vb.z;
                    o[i][3] += pc[i] * vb.w;
                }
            }
        }
    }

#pragma unroll
    for (int i = 0; i < 4; ++i) {
        const int qrow = q0 + ty * 4 + i;
        const float inv = 1.0f / l_i[i];
        float4 r;
        r.x = o[i][0] * inv;
        r.y = o[i][1] * inv;
        r.z = o[i][2] * inv;
        r.w = o[i][3] * inv;
        *(float4*)(y + base + (size_t)qrow * Cc + tx * 4) = r;
    }
}

// ---------------------------------------------------------------------------
extern "C" void kernel_launch(void* const* d_in, const int* in_sizes, int n_in,
                              void* d_out, int out_size, void* d_ws, size_t ws_size,
                              hipStream_t stream)
{
    const float* x    = (const float*)d_in[0];
    const float* padj = (const float*)d_in[1];
    const float* Wq   = (const float*)d_in[2];
    const float* bq   = (const float*)d_in[3];
    const float* Wk   = (const float*)d_in[4];
    const float* bk   = (const float*)d_in[5];
    const float* Wv   = (const float*)d_in[6];
    const float* bv   = (const float*)d_in[7];
    const float* Wp   = (const float*)d_in[8];
    const float* bp   = (const float*)d_in[9];
    float* out = (float*)d_out;

    const size_t MB = 1024 * 1024;
    char* ws = (char*)d_ws;
    short* Axp  = (short*)(ws);            // 24 MB: x-split; reused later for y-split
    short* Btq  = (short*)(ws + 24 * MB);  // 6 MB each
    short* Btk  = (short*)(ws + 30 * MB);
    short* Btv  = (short*)(ws + 36 * MB);
    short* Btp  = (short*)(ws + 42 * MB);
    float* qbuf = (float*)(ws + 48 * MB);  // 16 MB each
    float* kbuf = (float*)(ws + 64 * MB);
    float* vbuf = (float*)(ws + 80 * MB);
    float* ybuf = (float*)(ws + 96 * MB);  // 16 MB -> total 112 MB

    // split x into [hi | lo | hi] bf16
    split_hi_lo<<<4096, 256, 0, stream>>>(x, Axp);

    // transpose+split all four weights into [hi | hi | lo] bf16 (B^T layout)
    WPtrs wp;
    wp.W[0] = Wq; wp.W[1] = Wk; wp.W[2] = Wv; wp.W[3] = Wp;
    wp.Bt[0] = Btq; wp.Bt[1] = Btk; wp.Bt[2] = Btv; wp.Bt[3] = Btp;
    transpose_split<<<dim3(16, 16, 4), 256, 0, stream>>>(wp);

    // QKV projections via compensated bf16 MFMA GEMM
    GemmB g1;
    g1.Bt[0] = Btq; g1.Bt[1] = Btk; g1.Bt[2] = Btv;
    g1.bias[0] = bq; g1.bias[1] = bk; g1.bias[2] = bv;
    g1.out[0] = qbuf; g1.out[1] = kbuf; g1.out[2] = vbuf;
    gemm_mfma<<<dim3(8, 32, 3), 256, 0, stream>>>(Axp, g1);

    // masked attention (fp32)
    attn_kernel<<<dim3(Tt / 64, Bb * Hh), 256, 0, stream>>>(qbuf, kbuf, vbuf, padj, ybuf);

    // split attention output, then output projection
    split_hi_lo<<<4096, 256, 0, stream>>>(ybuf, Axp);
    GemmB g2;
    g2.Bt[0] = Btp; g2.Bt[1] = Btp; g2.Bt[2] = Btp;
    g2.bias[0] = bp; g2.bias[1] = bp; g2.bias[2] = bp;
    g2.out[0] = out; g2.out[1] = out; g2.out[2] = out;
    gemm_mfma<<<dim3(8, 32, 1), 256, 0, stream>>>(Axp, g2);
}

// Round 3
// 322.688 us; speedup vs baseline: 2.6725x; 1.6620x over previous
//
#include <hip/hip_runtime.h>
#include <hip/hip_bf16.h>
#include <math.h>

// Problem constants
#define Bb 4
#define Tt 1024
#define Cc 1024
#define Hh 16
#define Dd 64
#define K3 3072   // compensated-bf16 extended K for the final projection

typedef __attribute__((ext_vector_type(8))) short short8;
typedef __attribute__((ext_vector_type(4))) float floatx4;

__device__ __forceinline__ ushort bf16_rne(float f) {
    union { float f; unsigned u; } v; v.f = f;
    unsigned u = v.u;
    u += 0x7fffu + ((u >> 16) & 1u);
    return (ushort)(u >> 16);
}
__device__ __forceinline__ float bf16_to_f(ushort h) {
    union { float f; unsigned u; } v; v.u = ((unsigned)h) << 16;
    return v.f;
}
__device__ __forceinline__ void gl2lds16(const short* g, short* l) {
    __builtin_amdgcn_global_load_lds(
        (const __attribute__((address_space(1))) void*)g,
        (__attribute__((address_space(3))) void*)l,
        16, 0, 0);
}

// ---------------------------------------------------------------------------
// convert_bf16: x fp32 -> xb bf16, 8 elems/thread. grid 2048 x 256.
// ---------------------------------------------------------------------------
__global__ __launch_bounds__(256) void convert_bf16(const float* __restrict__ s,
                                                    short* __restrict__ d)
{
    const size_t i = ((size_t)blockIdx.x * 256 + threadIdx.x) * 8;
    float4 a = *(const float4*)(s + i);
    float4 b = *(const float4*)(s + i + 4);
    ushort4 h0 = make_ushort4(bf16_rne(a.x), bf16_rne(a.y), bf16_rne(a.z), bf16_rne(a.w));
    ushort4 h1 = make_ushort4(bf16_rne(b.x), bf16_rne(b.y), bf16_rne(b.z), bf16_rne(b.w));
    *(ushort4*)((ushort*)d + i)     = h0;
    *(ushort4*)((ushort*)d + i + 4) = h1;
}

// ---------------------------------------------------------------------------
// prep_weights: z<3 -> plain bf16 transpose Wt[n][k=1024] (Wq,Wk,Wv);
//               z==3 -> compensated [hi|hi|lo] K3 transpose for Wp.
// grid (16,16,4) x 256.
// ---------------------------------------------------------------------------
struct WPrep { const float* W[4]; short* out[4]; };

__global__ __launch_bounds__(256) void prep_weights(WPrep p)
{
    const int z = blockIdx.z;
    const float* __restrict__ W = p.W[z];
    ushort* __restrict__ outp = (ushort*)p.out[z];
    __shared__ float tile[64][65];
    const int k0  = blockIdx.y * 64;
    const int n0  = blockIdx.x * 64;
    const int tr  = threadIdx.x >> 4;
    const int tc4 = (threadIdx.x & 15) * 4;

#pragma unroll
    for (int i = 0; i < 4; ++i) {
        const int kk = tr + i * 16;
        float4 v = *(const float4*)(W + (size_t)(k0 + kk) * 1024 + n0 + tc4);
        tile[kk][tc4 + 0] = v.x;
        tile[kk][tc4 + 1] = v.y;
        tile[kk][tc4 + 2] = v.z;
        tile[kk][tc4 + 3] = v.w;
    }
    __syncthreads();
#pragma unroll
    for (int i = 0; i < 4; ++i) {
        const int n = tr + i * 16;
        ushort hv[4], lv[4];
#pragma unroll
        for (int c = 0; c < 4; ++c) {
            const float f = tile[tc4 + c][n];
            hv[c] = bf16_rne(f);
            lv[c] = bf16_rne(f - bf16_to_f(hv[c]));
        }
        ushort4 h4 = make_ushort4(hv[0], hv[1], hv[2], hv[3]);
        ushort4 l4 = make_ushort4(lv[0], lv[1], lv[2], lv[3]);
        if (z < 3) {
            *(ushort4*)(outp + (size_t)(n0 + n) * 1024 + k0 + tc4) = h4;
        } else {
            ushort* row = outp + (size_t)(n0 + n) * K3 + k0 + tc4;
            *(ushort4*)(row)        = h4;
            *(ushort4*)(row + 1024) = h4;
            *(ushort4*)(row + 2048) = l4;
        }
    }
}

// ---------------------------------------------------------------------------
// gemm_qkv: [4096,1024]bf16 @ Wt[z]^T + bias -> bf16 head-split outputs.
// z=0 -> qb[B*H][T][D]; z=1 -> kb same; z=2 -> vt[B*H][D][T] (transposed).
// 128x128 tile, BK=32, k-major chunk LDS layout (conflict-free frag reads).
// grid (8,32,3) x 256.
// ---------------------------------------------------------------------------
struct QkvP { const short* Wt[3]; const float* bias[3]; short* qb; short* kb; short* vt; };

__global__ __launch_bounds__(256) void gemm_qkv(const short* __restrict__ xb, QkvP p)
{
    const int z = blockIdx.z;
    const short* __restrict__ Wt   = p.Wt[z];
    const float* __restrict__ bias = p.bias[z];

    __shared__ __align__(16) short As[4096];   // [kc 0..3][row 0..127] 16B chunks
    __shared__ __align__(16) short Bs[4096];

    const int tid  = threadIdx.x;
    const int lane = tid & 63;
    const int w    = tid >> 6;
    const int wr   = w >> 1, wc = w & 1;
    const int quad = lane >> 4;
    const int l15  = lane & 15;
    const int bm   = blockIdx.y * 128;
    const int bn   = blockIdx.x * 128;

    const int c0 = tid, c1 = tid + 256;
    const short* Ag0 = xb + (size_t)(bm + (c0 & 127)) * 1024 + (c0 >> 7) * 8;
    const short* Ag1 = xb + (size_t)(bm + (c1 & 127)) * 1024 + (c1 >> 7) * 8;
    const short* Bg0 = Wt + (size_t)(bn + (c0 & 127)) * 1024 + (c0 >> 7) * 8;
    const short* Bg1 = Wt + (size_t)(bn + (c1 & 127)) * 1024 + (c1 >> 7) * 8;
    short* Ad0 = As + (c0 >> 6) * 512;   // wave-uniform
    short* Ad1 = As + (c1 >> 6) * 512;
    short* Bd0 = Bs + (c0 >> 6) * 512;
    short* Bd1 = Bs + (c1 >> 6) * 512;

    floatx4 acc[4][4];
#pragma unroll
    for (int i = 0; i < 4; ++i)
#pragma unroll
        for (int j = 0; j < 4; ++j)
            acc[i][j] = (floatx4){0.f, 0.f, 0.f, 0.f};

    for (int kt = 0; kt < 1024; kt += 32) {
        gl2lds16(Ag0 + kt, Ad0);
        gl2lds16(Ag1 + kt, Ad1);
        gl2lds16(Bg0 + kt, Bd0);
        gl2lds16(Bg1 + kt, Bd1);
        __syncthreads();

        short8 a[4], b[4];
#pragma unroll
        for (int i = 0; i < 4; ++i)
            a[i] = *(const short8*)&As[(quad * 128 + wr * 64 + i * 16 + l15) * 8];
#pragma unroll
        for (int j = 0; j < 4; ++j)
            b[j] = *(const short8*)&Bs[(quad * 128 + wc * 64 + j * 16 + l15) * 8];

#pragma unroll
        for (int i = 0; i < 4; ++i)
#pragma unroll
            for (int j = 0; j < 4; ++j)
                acc[i][j] = __builtin_amdgcn_mfma_f32_16x16x32_bf16(a[i], b[j], acc[i][j], 0, 0, 0);

        __syncthreads();
    }

    // epilogue: bf16, head-split layouts
    if (z == 2) {
        // vt[(bh*64+d)*1024 + t], pack 4 contiguous t per store
#pragma unroll
        for (int j = 0; j < 4; ++j) {
            const int col = bn + wc * 64 + j * 16 + l15;
            const int h = col >> 6, dd = col & 63;
            const float bj = bias[col];
#pragma unroll
            for (int i = 0; i < 4; ++i) {
                const int t0 = bm + wr * 64 + i * 16 + quad * 4;
                const int bi = t0 >> 10, t = t0 & 1023;
                ushort4 pk;
                pk.x = bf16_rne(acc[i][j][0] + bj);
                pk.y = bf16_rne(acc[i][j][1] + bj);
                pk.z = bf16_rne(acc[i][j][2] + bj);
                pk.w = bf16_rne(acc[i][j][3] + bj);
                *(ushort4*)((ushort*)p.vt + ((size_t)(bi * 16 + h) * 64 + dd) * 1024 + t) = pk;
            }
        }
    } else {
        ushort* outp = (ushort*)((z == 0) ? p.qb : p.kb);
#pragma unroll
        for (int j = 0; j < 4; ++j) {
            const int col = bn + wc * 64 + j * 16 + l15;
            const int h = col >> 6, dd = col & 63;
            const float bj = bias[col];
#pragma unroll
            for (int i = 0; i < 4; ++i) {
#pragma unroll
                for (int r = 0; r < 4; ++r) {
                    const int tg = bm + wr * 64 + i * 16 + quad * 4 + r;
                    const int bi = tg >> 10, t = tg & 1023;
                    outp[((size_t)(bi * 16 + h) * 1024 + t) * 64 + dd] =
                        bf16_rne(acc[i][j][r] + bj);
                }
            }
        }
    }
}

// ---------------------------------------------------------------------------
// attn_mfma: flash-style masked attention, bf16 MFMA + fp32 online softmax.
// Block = 256 thr = 4 waves; 128 q-rows/block; 16 key-tiles of 64.
// Epilogue fuses the [hi|lo|hi] split of y for the final projection.
// grid (8, 64) x 256.
// ---------------------------------------------------------------------------
__global__ __launch_bounds__(256) void attn_mfma(
    const short* __restrict__ qb, const short* __restrict__ kb,
    const short* __restrict__ vt, const float* __restrict__ padj,
    short* __restrict__ ysplit)
{
    __shared__ __align__(16) short Qs[8192];   // [kc_d 0..7][qrow 0..127]
    __shared__ __align__(16) short Ks[4096];   // [kc_d 0..7][key 0..63]
    __shared__ __align__(16) short Vt[4096];   // [kc_key 0..7][d 0..63]
    __shared__ __align__(16) short Ps[8192];   // [kc_key 0..7][qrow 0..127]
    __shared__ float keepq_s[128];
    __shared__ float keepk_s[64];

    const int tid  = threadIdx.x;
    const int lane = tid & 63;
    const int w    = tid >> 6;
    const int quad = lane >> 4;
    const int l15  = lane & 15;
    const int q0   = blockIdx.x * 128;
    const int bh   = blockIdx.y;
    const int b    = bh >> 4;
    const int h    = bh & 15;

    const short* qbase = qb + (size_t)bh * Tt * Dd;
    const short* kbase = kb + (size_t)bh * Tt * Dd;
    const short* vbase = vt + (size_t)bh * Dd * Tt;

    // stage Q tile (16 KB), k-major chunks
#pragma unroll
    for (int it = 0; it < 4; ++it) {
        const int c = it * 256 + tid;
        const int row = c & 127, kc = c >> 7;
        gl2lds16(qbase + (size_t)(q0 + row) * 64 + kc * 8, Qs + (c >> 6) * 512);
    }
    if (tid < 128) keepq_s[tid] = 1.0f - padj[b * Tt + q0 + tid];

    floatx4 O[2][4];
    float m_i[2][4], l_i[2][4];
#pragma unroll
    for (int mi = 0; mi < 2; ++mi) {
#pragma unroll
        for (int dj = 0; dj < 4; ++dj) O[mi][dj] = (floatx4){0.f, 0.f, 0.f, 0.f};
#pragma unroll
        for (int r = 0; r < 4; ++r) { m_i[mi][r] = -INFINITY; l_i[mi][r] = 0.0f; }
    }

    for (int kt = 0; kt < Tt; kt += 64) {
        __syncthreads();   // (A) prev PV done; Ks/Vt/Ps free; Q staging drained (1st iter)

#pragma unroll
        for (int it = 0; it < 2; ++it) {
            const int c = it * 256 + tid;
            const int key = c & 63, kc = c >> 6;
            gl2lds16(kbase + (size_t)(kt + key) * 64 + kc * 8, Ks + (c >> 6) * 512);
        }
#pragma unroll
        for (int it = 0; it < 2; ++it) {
            const int c = it * 256 + tid;
            const int dd = c & 63, kc = c >> 6;
            gl2lds16(vbase + (size_t)dd * 1024 + kt + kc * 8, Vt + (c >> 6) * 512);
        }
        if (tid < 64) keepk_s[tid] = 1.0f - padj[b * Tt + kt + tid];
        __syncthreads();   // (B) staging visible

        // ---- S = Q K^T ----
        floatx4 S[2][4];
#pragma unroll
        for (int mi = 0; mi < 2; ++mi)
#pragma unroll
            for (int nj = 0; nj < 4; ++nj)
                S[mi][nj] = (floatx4){0.f, 0.f, 0.f, 0.f};
#pragma unroll
        for (int ks = 0; ks < 2; ++ks) {
            short8 a[2], bb[4];
#pragma unroll
            for (int mi = 0; mi < 2; ++mi)
                a[mi] = *(const short8*)&Qs[((quad + 4 * ks) * 128 + w * 32 + mi * 16 + l15) * 8];
#pragma unroll
            for (int nj = 0; nj < 4; ++nj)
                bb[nj] = *(const short8*)&Ks[((quad + 4 * ks) * 64 + nj * 16 + l15) * 8];
#pragma unroll
            for (int mi = 0; mi < 2; ++mi)
#pragma unroll
                for (int nj = 0; nj < 4; ++nj)
                    S[mi][nj] = __builtin_amdgcn_mfma_f32_16x16x32_bf16(a[mi], bb[nj], S[mi][nj], 0, 0, 0);
        }

        // ---- mask + online softmax (fp32, registers) ----
        float kkv[4];
#pragma unroll
        for (int nj = 0; nj < 4; ++nj) kkv[nj] = keepk_s[nj * 16 + l15];

#pragma unroll
        for (int mi = 0; mi < 2; ++mi) {
#pragma unroll
            for (int r = 0; r < 4; ++r) {
                const int rowl = w * 32 + mi * 16 + quad * 4 + r;
                const float kq = keepq_s[rowl];
                float sv[4];
#pragma unroll
                for (int nj = 0; nj < 4; ++nj) {
                    const float x = S[mi][nj][r];
                    sv[nj] = (kq * kkv[nj] == 0.0f) ? -1e9f : x * 0.125f;
                }
                float rm = fmaxf(fmaxf(sv[0], sv[1]), fmaxf(sv[2], sv[3]));
#pragma unroll
                for (int off = 1; off < 16; off <<= 1)
                    rm = fmaxf(rm, __shfl_xor(rm, off));
                const float mo = m_i[mi][r];
                const float mn = fmaxf(mo, rm);
                const float al = __expf(mo - mn);
                m_i[mi][r] = mn;
                float rs = 0.0f;
#pragma unroll
                for (int nj = 0; nj < 4; ++nj) {
                    const float pv = __expf(sv[nj] - mn);
                    S[mi][nj][r] = pv;
                    rs += pv;
                }
#pragma unroll
                for (int off = 1; off < 16; off <<= 1)
                    rs += __shfl_xor(rs, off);
                l_i[mi][r] = l_i[mi][r] * al + rs;
#pragma unroll
                for (int dj = 0; dj < 4; ++dj) O[mi][dj][r] *= al;
            }
        }

        // ---- write P (bf16) to Ps, k-major layout ----
#pragma unroll
        for (int mi = 0; mi < 2; ++mi)
#pragma unroll
            for (int nj = 0; nj < 4; ++nj) {
                const int key = nj * 16 + l15;
#pragma unroll
                for (int r = 0; r < 4; ++r) {
                    const int rowl = w * 32 + mi * 16 + quad * 4 + r;
                    Ps[((key >> 3) * 128 + rowl) * 8 + (key & 7)] =
                        (short)bf16_rne(S[mi][nj][r]);
                }
            }
        __syncthreads();   // (C) P visible

        // ---- O += P V ----
#pragma unroll
        for (int ks = 0; ks < 2; ++ks) {
            short8 a[2], bv[4];
#pragma unroll
            for (int mi = 0; mi < 2; ++mi)
                a[mi] = *(const short8*)&Ps[((quad + 4 * ks) * 128 + w * 32 + mi * 16 + l15) * 8];
#pragma unroll
            for (int dj = 0; dj < 4; ++dj)
                bv[dj] = *(const short8*)&Vt[((quad + 4 * ks) * 64 + dj * 16 + l15) * 8];
#pragma unroll
            for (int mi = 0; mi < 2; ++mi)
#pragma unroll
                for (int dj = 0; dj < 4; ++dj)
                    O[mi][dj] = __builtin_amdgcn_mfma_f32_16x16x32_bf16(a[mi], bv[dj], O[mi][dj], 0, 0, 0);
        }
    }

    // ---- epilogue: normalize + fused [hi|lo|hi] split ----
#pragma unroll
    for (int mi = 0; mi < 2; ++mi) {
#pragma unroll
        for (int dj = 0; dj < 4; ++dj) {
            const int col = h * 64 + dj * 16 + l15;
#pragma unroll
            for (int r = 0; r < 4; ++r) {
                const int rowl = w * 32 + mi * 16 + quad * 4 + r;
                const int token = b * Tt + q0 + rowl;
                const float val = O[mi][dj][r] / l_i[mi][r];
                const ushort hi = bf16_rne(val);
                const ushort lo = bf16_rne(val - bf16_to_f(hi));
                ushort* yr = (ushort*)ysplit + (size_t)token * K3 + col;
                yr[0]    = hi;
                yr[1024] = lo;
                yr[2048] = hi;
            }
        }
    }
}

// ---------------------------------------------------------------------------
// gemm_proj: out[4096,1024]fp32 = ysplit[4096,3072] @ Wp_split^T + bp
// (compensated bf16, K3=3072, k-major chunk LDS). grid (8,32) x 256.
// ---------------------------------------------------------------------------
__global__ __launch_bounds__(256) void gemm_proj(const short* __restrict__ Ay,
                                                 const short* __restrict__ Bt,
                                                 const float* __restrict__ bias,
                                                 float* __restrict__ out)
{
    __shared__ __align__(16) short As[4096];
    __shared__ __align__(16) short Bs[4096];

    const int tid  = threadIdx.x;
    const int lane = tid & 63;
    const int w    = tid >> 6;
    const int wr   = w >> 1, wc = w & 1;
    const int quad = lane >> 4;
    const int l15  = lane & 15;
    const int bm   = blockIdx.y * 128;
    const int bn   = blockIdx.x * 128;

    const int c0 = tid, c1 = tid + 256;
    const short* Ag0 = Ay + (size_t)(bm + (c0 & 127)) * K3 + (c0 >> 7) * 8;
    const short* Ag1 = Ay + (size_t)(bm + (c1 & 127)) * K3 + (c1 >> 7) * 8;
    const short* Bg0 = Bt + (size_t)(bn + (c0 & 127)) * K3 + (c0 >> 7) * 8;
    const short* Bg1 = Bt + (size_t)(bn + (c1 & 127)) * K3 + (c1 >> 7) * 8;
    short* Ad0 = As + (c0 >> 6) * 512;
    short* Ad1 = As + (c1 >> 6) * 512;
    short* Bd0 = Bs + (c0 >> 6) * 512;
    short* Bd1 = Bs + (c1 >> 6) * 512;

    floatx4 acc[4][4];
#pragma unroll
    for (int i = 0; i < 4; ++i)
#pragma unroll
        for (int j = 0; j < 4; ++j)
            acc[i][j] = (floatx4){0.f, 0.f, 0.f, 0.f};

    for (int kt = 0; kt < K3; kt += 32) {
        gl2lds16(Ag0 + kt, Ad0);
        gl2lds16(Ag1 + kt, Ad1);
        gl2lds16(Bg0 + kt, Bd0);
        gl2lds16(Bg1 + kt, Bd1);
        __syncthreads();

        short8 a[4], b[4];
#pragma unroll
        for (int i = 0; i < 4; ++i)
            a[i] = *(const short8*)&As[(quad * 128 + wr * 64 + i * 16 + l15) * 8];
#pragma unroll
        for (int j = 0; j < 4; ++j)
            b[j] = *(const short8*)&Bs[(quad * 128 + wc * 64 + j * 16 + l15) * 8];

#pragma unroll
        for (int i = 0; i < 4; ++i)
#pragma unroll
            for (int j = 0; j < 4; ++j)
                acc[i][j] = __builtin_amdgcn_mfma_f32_16x16x32_bf16(a[i], b[j], acc[i][j], 0, 0, 0);

        __syncthreads();
    }

#pragma unroll
    for (int j = 0; j < 4; ++j) {
        const int col = bn + wc * 64 + j * 16 + l15;
        const float bj = bias[col];
#pragma unroll
        for (int i = 0; i < 4; ++i) {
            const int row = bm + wr * 64 + i * 16 + quad * 4;
            float* o = out + (size_t)row * 1024 + col;
#pragma unroll
            for (int r = 0; r < 4; ++r)
                o[(size_t)r * 1024] = acc[i][j][r] + bj;
        }
    }
}

// ---------------------------------------------------------------------------
extern "C" void kernel_launch(void* const* d_in, const int* in_sizes, int n_in,
                              void* d_out, int out_size, void* d_ws, size_t ws_size,
                              hipStream_t stream)
{
    const float* x    = (const float*)d_in[0];
    const float* padj = (const float*)d_in[1];
    const float* Wq   = (const float*)d_in[2];
    const float* bq   = (const float*)d_in[3];
    const float* Wk   = (const float*)d_in[4];
    const float* bk   = (const float*)d_in[5];
    const float* Wv   = (const float*)d_in[6];
    const float* bv   = (const float*)d_in[7];
    const float* Wp   = (const float*)d_in[8];
    const float* bp   = (const float*)d_in[9];
    float* out = (float*)d_out;

    const size_t MB = 1024 * 1024;
    char* ws = (char*)d_ws;
    short* xb  = (short*)(ws);             //  8 MB
    short* Wt0 = (short*)(ws +  8 * MB);   //  2 MB
    short* Wt1 = (short*)(ws + 10 * MB);   //  2 MB
    short* Wt2 = (short*)(ws + 12 * MB);   //  2 MB
    short* Wtp = (short*)(ws + 14 * MB);   //  6 MB (K3 split)
    short* qb  = (short*)(ws + 20 * MB);   //  8 MB
    short* kb  = (short*)(ws + 28 * MB);   //  8 MB
    short* vtb = (short*)(ws + 36 * MB);   //  8 MB
    short* ysp = (short*)(ws + 44 * MB);   // 24 MB (K3 split)  -> 68 MB total

    convert_bf16<<<2048, 256, 0, stream>>>(x, xb);

    WPrep wp;
    wp.W[0] = Wq; wp.W[1] = Wk; wp.W[2] = Wv; wp.W[3] = Wp;
    wp.out[0] = Wt0; wp.out[1] = Wt1; wp.out[2] = Wt2; wp.out[3] = Wtp;
    prep_weights<<<dim3(16, 16, 4), 256, 0, stream>>>(wp);

    QkvP qp;
    qp.Wt[0] = Wt0; qp.Wt[1] = Wt1; qp.Wt[2] = Wt2;
    qp.bias[0] = bq; qp.bias[1] = bk; qp.bias[2] = bv;
    qp.qb = qb; qp.kb = kb; qp.vt = vtb;
    gemm_qkv<<<dim3(8, 32, 3), 256, 0, stream>>>(xb, qp);

    attn_mfma<<<dim3(8, 64), 256, 0, stream>>>(qb, kb, vtb, padj, ysp);

    gemm_proj<<<dim3(8, 32), 256, 0, stream>>>(ysp, Wtp, bp, out);
}

// Round 4
// 314.301 us; speedup vs baseline: 2.7438x; 1.0267x over previous
//
#include <hip/hip_runtime.h>
#include <hip/hip_bf16.h>
#include <math.h>

// Problem constants
#define Bb 4
#define Tt 1024
#define Cc 1024
#define Hh 16
#define Dd 64
#define K3 3072   // compensated-bf16 extended K for the final projection

typedef __attribute__((ext_vector_type(8))) short short8;
typedef __attribute__((ext_vector_type(4))) float floatx4;

__device__ __forceinline__ ushort bf16_rne(float f) {
    union { float f; unsigned u; } v; v.f = f;
    unsigned u = v.u;
    u += 0x7fffu + ((u >> 16) & 1u);
    return (ushort)(u >> 16);
}
__device__ __forceinline__ float bf16_to_f(ushort h) {
    union { float f; unsigned u; } v; v.u = ((unsigned)h) << 16;
    return v.f;
}
__device__ __forceinline__ void gl2lds16(const short* g, short* l) {
    __builtin_amdgcn_global_load_lds(
        (const __attribute__((address_space(1))) void*)g,
        (__attribute__((address_space(3))) void*)l,
        16, 0, 0);
}

// ---------------------------------------------------------------------------
// convert_bf16: x fp32 -> xb bf16, 8 elems/thread. grid 2048 x 256.
// ---------------------------------------------------------------------------
__global__ __launch_bounds__(256) void convert_bf16(const float* __restrict__ s,
                                                    short* __restrict__ d)
{
    const size_t i = ((size_t)blockIdx.x * 256 + threadIdx.x) * 8;
    float4 a = *(const float4*)(s + i);
    float4 b = *(const float4*)(s + i + 4);
    ushort4 h0 = make_ushort4(bf16_rne(a.x), bf16_rne(a.y), bf16_rne(a.z), bf16_rne(a.w));
    ushort4 h1 = make_ushort4(bf16_rne(b.x), bf16_rne(b.y), bf16_rne(b.z), bf16_rne(b.w));
    *(ushort4*)((ushort*)d + i)     = h0;
    *(ushort4*)((ushort*)d + i + 4) = h1;
}

// ---------------------------------------------------------------------------
// prep_weights: z<3 -> plain bf16 transpose Wt[n][k=1024] (Wq,Wk,Wv);
//               z==3 -> compensated [hi|hi|lo] K3 transpose for Wp.
// grid (16,16,4) x 256.
// ---------------------------------------------------------------------------
struct WPrep { const float* W[4]; short* out[4]; };

__global__ __launch_bounds__(256) void prep_weights(WPrep p)
{
    const int z = blockIdx.z;
    const float* __restrict__ W = p.W[z];
    ushort* __restrict__ outp = (ushort*)p.out[z];
    __shared__ float tile[64][65];
    const int k0  = blockIdx.y * 64;
    const int n0  = blockIdx.x * 64;
    const int tr  = threadIdx.x >> 4;
    const int tc4 = (threadIdx.x & 15) * 4;

#pragma unroll
    for (int i = 0; i < 4; ++i) {
        const int kk = tr + i * 16;
        float4 v = *(const float4*)(W + (size_t)(k0 + kk) * 1024 + n0 + tc4);
        tile[kk][tc4 + 0] = v.x;
        tile[kk][tc4 + 1] = v.y;
        tile[kk][tc4 + 2] = v.z;
        tile[kk][tc4 + 3] = v.w;
    }
    __syncthreads();
#pragma unroll
    for (int i = 0; i < 4; ++i) {
        const int n = tr + i * 16;
        ushort hv[4], lv[4];
#pragma unroll
        for (int c = 0; c < 4; ++c) {
            const float f = tile[tc4 + c][n];
            hv[c] = bf16_rne(f);
            lv[c] = bf16_rne(f - bf16_to_f(hv[c]));
        }
        ushort4 h4 = make_ushort4(hv[0], hv[1], hv[2], hv[3]);
        ushort4 l4 = make_ushort4(lv[0], lv[1], lv[2], lv[3]);
        if (z < 3) {
            *(ushort4*)(outp + (size_t)(n0 + n) * 1024 + k0 + tc4) = h4;
        } else {
            ushort* row = outp + (size_t)(n0 + n) * K3 + k0 + tc4;
            *(ushort4*)(row)        = h4;
            *(ushort4*)(row + 1024) = h4;
            *(ushort4*)(row + 2048) = l4;
        }
    }
}

// ---------------------------------------------------------------------------
// gemm_qkv: [4096,1024]bf16 @ Wt[z]^T + bias -> bf16 head-split outputs.
// z=0 -> qb[B*H][T][D]; z=1 -> kb same; z=2 -> vt[B*H][D][T] (transposed).
// 128x128 tile, BK=32, k-major chunk LDS layout (conflict-free frag reads).
// grid (8,32,3) x 256.  768 blocks = 3/CU.
// ---------------------------------------------------------------------------
struct QkvP { const short* Wt[3]; const float* bias[3]; short* qb; short* kb; short* vt; };

__global__ __launch_bounds__(256) void gemm_qkv(const short* __restrict__ xb, QkvP p)
{
    const int z = blockIdx.z;
    const short* __restrict__ Wt   = p.Wt[z];
    const float* __restrict__ bias = p.bias[z];

    __shared__ __align__(16) short As[4096];   // [kc 0..3][row 0..127] 16B chunks
    __shared__ __align__(16) short Bs[4096];

    const int tid  = threadIdx.x;
    const int lane = tid & 63;
    const int w    = tid >> 6;
    const int wr   = w >> 1, wc = w & 1;
    const int quad = lane >> 4;
    const int l15  = lane & 15;
    const int bm   = blockIdx.y * 128;
    const int bn   = blockIdx.x * 128;

    const int c0 = tid, c1 = tid + 256;
    const short* Ag0 = xb + (size_t)(bm + (c0 & 127)) * 1024 + (c0 >> 7) * 8;
    const short* Ag1 = xb + (size_t)(bm + (c1 & 127)) * 1024 + (c1 >> 7) * 8;
    const short* Bg0 = Wt + (size_t)(bn + (c0 & 127)) * 1024 + (c0 >> 7) * 8;
    const short* Bg1 = Wt + (size_t)(bn + (c1 & 127)) * 1024 + (c1 >> 7) * 8;
    short* Ad0 = As + (c0 >> 6) * 512;   // wave-uniform
    short* Ad1 = As + (c1 >> 6) * 512;
    short* Bd0 = Bs + (c0 >> 6) * 512;
    short* Bd1 = Bs + (c1 >> 6) * 512;

    floatx4 acc[4][4];
#pragma unroll
    for (int i = 0; i < 4; ++i)
#pragma unroll
        for (int j = 0; j < 4; ++j)
            acc[i][j] = (floatx4){0.f, 0.f, 0.f, 0.f};

    for (int kt = 0; kt < 1024; kt += 32) {
        gl2lds16(Ag0 + kt, Ad0);
        gl2lds16(Ag1 + kt, Ad1);
        gl2lds16(Bg0 + kt, Bd0);
        gl2lds16(Bg1 + kt, Bd1);
        __syncthreads();

        short8 a[4], b[4];
#pragma unroll
        for (int i = 0; i < 4; ++i)
            a[i] = *(const short8*)&As[(quad * 128 + wr * 64 + i * 16 + l15) * 8];
#pragma unroll
        for (int j = 0; j < 4; ++j)
            b[j] = *(const short8*)&Bs[(quad * 128 + wc * 64 + j * 16 + l15) * 8];

#pragma unroll
        for (int i = 0; i < 4; ++i)
#pragma unroll
            for (int j = 0; j < 4; ++j)
                acc[i][j] = __builtin_amdgcn_mfma_f32_16x16x32_bf16(a[i], b[j], acc[i][j], 0, 0, 0);

        __syncthreads();
    }

    // epilogue: bf16, head-split layouts
    if (z == 2) {
        // vt[(bh*64+d)*1024 + t], pack 4 contiguous t per store
#pragma unroll
        for (int j = 0; j < 4; ++j) {
            const int col = bn + wc * 64 + j * 16 + l15;
            const int h = col >> 6, dd = col & 63;
            const float bj = bias[col];
#pragma unroll
            for (int i = 0; i < 4; ++i) {
                const int t0 = bm + wr * 64 + i * 16 + quad * 4;
                const int bi = t0 >> 10, t = t0 & 1023;
                ushort4 pk;
                pk.x = bf16_rne(acc[i][j][0] + bj);
                pk.y = bf16_rne(acc[i][j][1] + bj);
                pk.z = bf16_rne(acc[i][j][2] + bj);
                pk.w = bf16_rne(acc[i][j][3] + bj);
                *(ushort4*)((ushort*)p.vt + ((size_t)(bi * 16 + h) * 64 + dd) * 1024 + t) = pk;
            }
        }
    } else {
        ushort* outp = (ushort*)((z == 0) ? p.qb : p.kb);
#pragma unroll
        for (int j = 0; j < 4; ++j) {
            const int col = bn + wc * 64 + j * 16 + l15;
            const int h = col >> 6, dd = col & 63;
            const float bj = bias[col];
#pragma unroll
            for (int i = 0; i < 4; ++i) {
#pragma unroll
                for (int r = 0; r < 4; ++r) {
                    const int tg = bm + wr * 64 + i * 16 + quad * 4 + r;
                    const int bi = tg >> 10, t = tg & 1023;
                    outp[((size_t)(bi * 16 + h) * 1024 + t) * 64 + dd] =
                        bf16_rne(acc[i][j][r] + bj);
                }
            }
        }
    }
}

// ---------------------------------------------------------------------------
// attn_mfma: flash-style masked attention, bf16 MFMA + fp32 online softmax.
// Block = 256 thr = 4 waves; 128 q-rows/block; 16 key-tiles of 64.
// Epilogue fuses the [hi|lo|hi] split of y for the final projection.
// grid (8, 64) x 256.  512 blocks = 2/CU.
// ---------------------------------------------------------------------------
__global__ __launch_bounds__(256) void attn_mfma(
    const short* __restrict__ qb, const short* __restrict__ kb,
    const short* __restrict__ vt, const float* __restrict__ padj,
    short* __restrict__ ysplit)
{
    __shared__ __align__(16) short Qs[8192];   // [kc_d 0..7][qrow 0..127]
    __shared__ __align__(16) short Ks[4096];   // [kc_d 0..7][key 0..63]
    __shared__ __align__(16) short Vt[4096];   // [kc_key 0..7][d 0..63]
    __shared__ __align__(16) short Ps[8192];   // [kc_key 0..7][qrow 0..127]
    __shared__ float keepq_s[128];
    __shared__ float keepk_s[64];

    const int tid  = threadIdx.x;
    const int lane = tid & 63;
    const int w    = tid >> 6;
    const int quad = lane >> 4;
    const int l15  = lane & 15;
    const int q0   = blockIdx.x * 128;
    const int bh   = blockIdx.y;
    const int b    = bh >> 4;
    const int h    = bh & 15;

    const short* qbase = qb + (size_t)bh * Tt * Dd;
    const short* kbase = kb + (size_t)bh * Tt * Dd;
    const short* vbase = vt + (size_t)bh * Dd * Tt;

    // stage Q tile (16 KB), k-major chunks
#pragma unroll
    for (int it = 0; it < 4; ++it) {
        const int c = it * 256 + tid;
        const int row = c & 127, kc = c >> 7;
        gl2lds16(qbase + (size_t)(q0 + row) * 64 + kc * 8, Qs + (c >> 6) * 512);
    }
    if (tid < 128) keepq_s[tid] = 1.0f - padj[b * Tt + q0 + tid];

    floatx4 O[2][4];
    float m_i[2][4], l_i[2][4];
#pragma unroll
    for (int mi = 0; mi < 2; ++mi) {
#pragma unroll
        for (int dj = 0; dj < 4; ++dj) O[mi][dj] = (floatx4){0.f, 0.f, 0.f, 0.f};
#pragma unroll
        for (int r = 0; r < 4; ++r) { m_i[mi][r] = -INFINITY; l_i[mi][r] = 0.0f; }
    }

    for (int kt = 0; kt < Tt; kt += 64) {
        __syncthreads();   // (A) prev PV done; Ks/Vt/Ps free; Q staging drained (1st iter)

#pragma unroll
        for (int it = 0; it < 2; ++it) {
            const int c = it * 256 + tid;
            const int key = c & 63, kc = c >> 6;
            gl2lds16(kbase + (size_t)(kt + key) * 64 + kc * 8, Ks + (c >> 6) * 512);
        }
#pragma unroll
        for (int it = 0; it < 2; ++it) {
            const int c = it * 256 + tid;
            const int dd = c & 63, kc = c >> 6;
            gl2lds16(vbase + (size_t)dd * 1024 + kt + kc * 8, Vt + (c >> 6) * 512);
        }
        if (tid < 64) keepk_s[tid] = 1.0f - padj[b * Tt + kt + tid];
        __syncthreads();   // (B) staging visible

        // ---- S = Q K^T ----
        floatx4 S[2][4];
#pragma unroll
        for (int mi = 0; mi < 2; ++mi)
#pragma unroll
            for (int nj = 0; nj < 4; ++nj)
                S[mi][nj] = (floatx4){0.f, 0.f, 0.f, 0.f};
#pragma unroll
        for (int ks = 0; ks < 2; ++ks) {
            short8 a[2], bb[4];
#pragma unroll
            for (int mi = 0; mi < 2; ++mi)
                a[mi] = *(const short8*)&Qs[((quad + 4 * ks) * 128 + w * 32 + mi * 16 + l15) * 8];
#pragma unroll
            for (int nj = 0; nj < 4; ++nj)
                bb[nj] = *(const short8*)&Ks[((quad + 4 * ks) * 64 + nj * 16 + l15) * 8];
#pragma unroll
            for (int mi = 0; mi < 2; ++mi)
#pragma unroll
                for (int nj = 0; nj < 4; ++nj)
                    S[mi][nj] = __builtin_amdgcn_mfma_f32_16x16x32_bf16(a[mi], bb[nj], S[mi][nj], 0, 0, 0);
        }

        // ---- mask + online softmax (fp32, registers) ----
        float kkv[4];
#pragma unroll
        for (int nj = 0; nj < 4; ++nj) kkv[nj] = keepk_s[nj * 16 + l15];

#pragma unroll
        for (int mi = 0; mi < 2; ++mi) {
#pragma unroll
            for (int r = 0; r < 4; ++r) {
                const int rowl = w * 32 + mi * 16 + quad * 4 + r;
                const float kq = keepq_s[rowl];
                float sv[4];
#pragma unroll
                for (int nj = 0; nj < 4; ++nj) {
                    const float x = S[mi][nj][r];
                    sv[nj] = (kq * kkv[nj] == 0.0f) ? -1e9f : x * 0.125f;
                }
                float rm = fmaxf(fmaxf(sv[0], sv[1]), fmaxf(sv[2], sv[3]));
#pragma unroll
                for (int off = 1; off < 16; off <<= 1)
                    rm = fmaxf(rm, __shfl_xor(rm, off));
                const float mo = m_i[mi][r];
                const float mn = fmaxf(mo, rm);
                const float al = __expf(mo - mn);
                m_i[mi][r] = mn;
                float rs = 0.0f;
#pragma unroll
                for (int nj = 0; nj < 4; ++nj) {
                    const float pv = __expf(sv[nj] - mn);
                    S[mi][nj][r] = pv;
                    rs += pv;
                }
#pragma unroll
                for (int off = 1; off < 16; off <<= 1)
                    rs += __shfl_xor(rs, off);
                l_i[mi][r] = l_i[mi][r] * al + rs;
#pragma unroll
                for (int dj = 0; dj < 4; ++dj) O[mi][dj][r] *= al;
            }
        }

        // ---- write P (bf16) to Ps, k-major layout ----
#pragma unroll
        for (int mi = 0; mi < 2; ++mi)
#pragma unroll
            for (int nj = 0; nj < 4; ++nj) {
                const int key = nj * 16 + l15;
#pragma unroll
                for (int r = 0; r < 4; ++r) {
                    const int rowl = w * 32 + mi * 16 + quad * 4 + r;
                    Ps[((key >> 3) * 128 + rowl) * 8 + (key & 7)] =
                        (short)bf16_rne(S[mi][nj][r]);
                }
            }
        __syncthreads();   // (C) P visible

        // ---- O += P V ----
#pragma unroll
        for (int ks = 0; ks < 2; ++ks) {
            short8 a[2], bv[4];
#pragma unroll
            for (int mi = 0; mi < 2; ++mi)
                a[mi] = *(const short8*)&Ps[((quad + 4 * ks) * 128 + w * 32 + mi * 16 + l15) * 8];
#pragma unroll
            for (int dj = 0; dj < 4; ++dj)
                bv[dj] = *(const short8*)&Vt[((quad + 4 * ks) * 64 + dj * 16 + l15) * 8];
#pragma unroll
            for (int mi = 0; mi < 2; ++mi)
#pragma unroll
                for (int dj = 0; dj < 4; ++dj)
                    O[mi][dj] = __builtin_amdgcn_mfma_f32_16x16x32_bf16(a[mi], bv[dj], O[mi][dj], 0, 0, 0);
        }
    }

    // ---- epilogue: normalize + fused [hi|lo|hi] split ----
#pragma unroll
    for (int mi = 0; mi < 2; ++mi) {
#pragma unroll
        for (int dj = 0; dj < 4; ++dj) {
            const int col = h * 64 + dj * 16 + l15;
#pragma unroll
            for (int r = 0; r < 4; ++r) {
                const int rowl = w * 32 + mi * 16 + quad * 4 + r;
                const int token = b * Tt + q0 + rowl;
                const float val = O[mi][dj][r] / l_i[mi][r];
                const ushort hi = bf16_rne(val);
                const ushort lo = bf16_rne(val - bf16_to_f(hi));
                ushort* yr = (ushort*)ysplit + (size_t)token * K3 + col;
                yr[0]    = hi;
                yr[1024] = lo;
                yr[2048] = hi;
            }
        }
    }
}

// ---------------------------------------------------------------------------
// gemm_proj: out[4096,1024]fp32 = ysplit[4096,3072] @ Wp_split^T + bp
// (compensated bf16, K3=3072, k-major chunk LDS).
// RETILED round 4: 128x64 (MxN) tiles, grid (16,32) = 512 blocks = 2/CU
// (was 128x128 @ 256 blocks = 1/CU -> fully exposed barrier drains,
//  MfmaUtil 11%). 4 waves, each 32 rows x 64 cols = 2x4 frags.
// ---------------------------------------------------------------------------
__global__ __launch_bounds__(256) void gemm_proj(const short* __restrict__ Ay,
                                                 const short* __restrict__ Bt,
                                                 const float* __restrict__ bias,
                                                 float* __restrict__ out)
{
    __shared__ __align__(16) short As[4096];   // [kc 0..3][row 0..127] 16B chunks
    __shared__ __align__(16) short Bs[2048];   // [kc 0..3][row 0..63]

    const int tid  = threadIdx.x;
    const int lane = tid & 63;
    const int w    = tid >> 6;
    const int quad = lane >> 4;
    const int l15  = lane & 15;
    const int bm   = blockIdx.y * 128;
    const int bn   = blockIdx.x * 64;

    // A: 512 chunks (c = kc*128 + row), threads stage c0=tid, c1=tid+256
    // B: 256 chunks (c = kc*64  + row), threads stage c=tid
    const int c0 = tid, c1 = tid + 256;
    const short* Ag0 = Ay + (size_t)(bm + (c0 & 127)) * K3 + (c0 >> 7) * 8;
    const short* Ag1 = Ay + (size_t)(bm + (c1 & 127)) * K3 + (c1 >> 7) * 8;
    const short* Bg0 = Bt + (size_t)(bn + (c0 & 63)) * K3 + (c0 >> 6) * 8;
    short* Ad0 = As + (c0 >> 6) * 512;   // wave-uniform bases
    short* Ad1 = As + (c1 >> 6) * 512;
    short* Bd0 = Bs + (c0 >> 6) * 512;

    floatx4 acc[2][4];
#pragma unroll
    for (int i = 0; i < 2; ++i)
#pragma unroll
        for (int j = 0; j < 4; ++j)
            acc[i][j] = (floatx4){0.f, 0.f, 0.f, 0.f};

    for (int kt = 0; kt < K3; kt += 32) {
        gl2lds16(Ag0 + kt, Ad0);
        gl2lds16(Ag1 + kt, Ad1);
        gl2lds16(Bg0 + kt, Bd0);
        __syncthreads();

        short8 a[2], b[4];
#pragma unroll
        for (int i = 0; i < 2; ++i)
            a[i] = *(const short8*)&As[(quad * 128 + w * 32 + i * 16 + l15) * 8];
#pragma unroll
        for (int j = 0; j < 4; ++j)
            b[j] = *(const short8*)&Bs[(quad * 64 + j * 16 + l15) * 8];

#pragma unroll
        for (int i = 0; i < 2; ++i)
#pragma unroll
            for (int j = 0; j < 4; ++j)
                acc[i][j] = __builtin_amdgcn_mfma_f32_16x16x32_bf16(a[i], b[j], acc[i][j], 0, 0, 0);

        __syncthreads();
    }

#pragma unroll
    for (int j = 0; j < 4; ++j) {
        const int col = bn + j * 16 + l15;
        const float bj = bias[col];
#pragma unroll
        for (int i = 0; i < 2; ++i) {
            const int row = bm + w * 32 + i * 16 + quad * 4;
            float* o = out + (size_t)row * 1024 + col;
#pragma unroll
            for (int r = 0; r < 4; ++r)
                o[(size_t)r * 1024] = acc[i][j][r] + bj;
        }
    }
}

// ---------------------------------------------------------------------------
extern "C" void kernel_launch(void* const* d_in, const int* in_sizes, int n_in,
                              void* d_out, int out_size, void* d_ws, size_t ws_size,
                              hipStream_t stream)
{
    const float* x    = (const float*)d_in[0];
    const float* padj = (const float*)d_in[1];
    const float* Wq   = (const float*)d_in[2];
    const float* bq   = (const float*)d_in[3];
    const float* Wk   = (const float*)d_in[4];
    const float* bk   = (const float*)d_in[5];
    const float* Wv   = (const float*)d_in[6];
    const float* bv   = (const float*)d_in[7];
    const float* Wp   = (const float*)d_in[8];
    const float* bp   = (const float*)d_in[9];
    float* out = (float*)d_out;

    const size_t MB = 1024 * 1024;
    char* ws = (char*)d_ws;
    short* xb  = (short*)(ws);             //  8 MB
    short* Wt0 = (short*)(ws +  8 * MB);   //  2 MB
    short* Wt1 = (short*)(ws + 10 * MB);   //  2 MB
    short* Wt2 = (short*)(ws + 12 * MB);   //  2 MB
    short* Wtp = (short*)(ws + 14 * MB);   //  6 MB (K3 split)
    short* qb  = (short*)(ws + 20 * MB);   //  8 MB
    short* kb  = (short*)(ws + 28 * MB);   //  8 MB
    short* vtb = (short*)(ws + 36 * MB);   //  8 MB
    short* ysp = (short*)(ws + 44 * MB);   // 24 MB (K3 split)  -> 68 MB total

    convert_bf16<<<2048, 256, 0, stream>>>(x, xb);

    WPrep wp;
    wp.W[0] = Wq; wp.W[1] = Wk; wp.W[2] = Wv; wp.W[3] = Wp;
    wp.out[0] = Wt0; wp.out[1] = Wt1; wp.out[2] = Wt2; wp.out[3] = Wtp;
    prep_weights<<<dim3(16, 16, 4), 256, 0, stream>>>(wp);

    QkvP qp;
    qp.Wt[0] = Wt0; qp.Wt[1] = Wt1; qp.Wt[2] = Wt2;
    qp.bias[0] = bq; qp.bias[1] = bk; qp.bias[2] = bv;
    qp.qb = qb; qp.kb = kb; qp.vt = vtb;
    gemm_qkv<<<dim3(8, 32, 3), 256, 0, stream>>>(xb, qp);

    attn_mfma<<<dim3(8, 64), 256, 0, stream>>>(qb, kb, vtb, padj, ysp);

    gemm_proj<<<dim3(16, 32), 256, 0, stream>>>(ysp, Wtp, bp, out);
}